// Round 2
// baseline (1004.620 us; speedup 1.0000x reference)
//
#include <hip/hip_runtime.h>
#include <stdint.h>

#define N_ROWS 32768
#define K_CB   8192
#define D_DIM  512
#define TAU    0.07f
#define BM     128
#define BK     32
#define NKT    (K_CB / BK)        // 256 k-tiles
#define RM_STRIDE 520             // u16 elems per s_rm row (1040 B, 16B-aligned)
#define CT_STRIDE 40              // u16 elems per s_ct row (80 B, 16B-aligned)
#define P_STRIDE  36              // u16 elems per P row (72 B; >=32 entries + pad, 8B-aligned)

typedef __attribute__((ext_vector_type(8))) short bf16x8;
typedef __attribute__((ext_vector_type(4))) short bf16x4;
typedef __attribute__((ext_vector_type(4))) float f32x4;

__device__ __forceinline__ unsigned short f2bf(float f) {
    unsigned u = __builtin_bit_cast(unsigned, f);
    u += 0x7FFFu + ((u >> 16) & 1u);          // round-to-nearest-even
    return (unsigned short)(u >> 16);
}

// codebook fp32 [K][512] -> bf16 row-major [K][512]  and  tile-transposed [j][512][32]
__global__ __launch_bounds__(512) void prep_codebook(const float* __restrict__ cb,
                                                     unsigned short* __restrict__ cb_rm,
                                                     unsigned short* __restrict__ cb_t) {
    __shared__ unsigned short tile[32 * 512];     // 32 KB, [kk][d]
    const int j = blockIdx.x;
    const int t = threadIdx.x;
    const float2* src = (const float2*)(cb + (size_t)j * (BK * D_DIM));
    unsigned* rm32 = (unsigned*)cb_rm + (size_t)j * (BK * D_DIM / 2);
    unsigned* t32  = (unsigned*)tile;
    #pragma unroll
    for (int it = 0; it < 16; ++it) {
        int e2 = it * 512 + t;                    // pair index: kk = (2*e2)>>9, d = (2*e2)&511
        float2 v = src[e2];
        unsigned pk = (unsigned)f2bf(v.x) | ((unsigned)f2bf(v.y) << 16);
        rm32[e2] = pk;                            // coalesced
        t32[e2]  = pk;
    }
    __syncthreads();
    // thread t == d: gather 32 kk's, write 64B contiguous
    unsigned outp[16];
    #pragma unroll
    for (int i = 0; i < 16; ++i) {
        unsigned lo = tile[(2 * i) * 512 + t];
        unsigned hi = tile[(2 * i + 1) * 512 + t];
        outp[i] = lo | (hi << 16);
    }
    uint4* dst = (uint4*)(cb_t + (size_t)j * (BK * D_DIM) + t * 32);
    #pragma unroll
    for (int i = 0; i < 4; ++i) dst[i] = ((uint4*)outp)[i];
}

__global__ __launch_bounds__(512, 2) void cbmap_main(const float* __restrict__ x,
                                                     const unsigned short* __restrict__ cb_rm,
                                                     const unsigned short* __restrict__ cb_t,
                                                     float* __restrict__ out) {
    __shared__ unsigned short s_rm[BK * RM_STRIDE];     // 33280 B: C-tile row-major [cb][d]
    __shared__ unsigned short s_ct[D_DIM * CT_STRIDE];  // 40960 B: C-tile transposed [d][cb]
    __shared__ unsigned short s_p[8 * 16 * P_STRIDE];   //  9216 B: wave-private P [xr][cb]

    const int tid  = threadIdx.x;
    const int w    = tid >> 6;
    const int lane = tid & 63;
    const int l15  = lane & 15;
    const int q    = lane >> 4;
    const int wr0  = blockIdx.x * BM + w * 16;          // this wave's 16 x-rows

    // ---- prologue: L2-normalize own rows, fold in 1/TAU, build A-fragments (regs)
    const float* xrow = x + (size_t)(wr0 + l15) * D_DIM + q * 8;
    float4 va[16], vb[16];
    float ss = 0.f;
    #pragma unroll
    for (int k = 0; k < 16; ++k) {
        va[k] = *(const float4*)(xrow + k * 32);
        vb[k] = *(const float4*)(xrow + k * 32 + 4);
        ss += va[k].x*va[k].x + va[k].y*va[k].y + va[k].z*va[k].z + va[k].w*va[k].w;
        ss += vb[k].x*vb[k].x + vb[k].y*vb[k].y + vb[k].z*vb[k].z + vb[k].w*vb[k].w;
    }
    ss += __shfl_xor(ss, 16, 64);
    ss += __shfl_xor(ss, 32, 64);
    const float scale = 1.0f / (fmaxf(sqrtf(ss), 1e-12f) * TAU);
    bf16x8 afrag[16];
    #pragma unroll
    for (int k = 0; k < 16; ++k) {
        bf16x8 f;
        f[0] = (short)f2bf(va[k].x * scale); f[1] = (short)f2bf(va[k].y * scale);
        f[2] = (short)f2bf(va[k].z * scale); f[3] = (short)f2bf(va[k].w * scale);
        f[4] = (short)f2bf(vb[k].x * scale); f[5] = (short)f2bf(vb[k].y * scale);
        f[6] = (short)f2bf(vb[k].z * scale); f[7] = (short)f2bf(vb[k].w * scale);
        afrag[k] = f;
    }

    f32x4 acc[32];
    #pragma unroll
    for (int i = 0; i < 32; ++i) acc[i] = (f32x4){0.f, 0.f, 0.f, 0.f};
    float dsum[4] = {0.f, 0.f, 0.f, 0.f};

    // staging pointers: thread t copies 64B of each layout per k-tile
    const uint4* gA = (const uint4*)cb_rm + tid * 4;
    const uint4* gB = (const uint4*)cb_t + tid * 4;
    uint4* dA = (uint4*)&s_rm[(tid >> 4) * RM_STRIDE + (tid & 15) * 32];
    uint4* dB = (uint4*)&s_ct[tid * CT_STRIDE];
    unsigned short* prow = &s_p[w * (16 * P_STRIDE)];

    for (int j = 0; j < NKT; ++j) {
        __syncthreads();                         // previous tile's compute done
        uint4 a0 = gA[0], a1 = gA[1], a2 = gA[2], a3 = gA[3];
        uint4 b0 = gB[0], b1 = gB[1], b2 = gB[2], b3 = gB[3];
        gA += 2048; gB += 2048;
        dA[0] = a0; dA[1] = a1; dA[2] = a2; dA[3] = a3;
        dB[0] = b0; dB[1] = b1; dB[2] = b2; dB[3] = b3;
        __syncthreads();

        // ---- S = (x_n/tau) @ C^T : two 16x16 n-tiles over K=512
        f32x4 s0 = (f32x4){0.f,0.f,0.f,0.f};
        f32x4 s1 = (f32x4){0.f,0.f,0.f,0.f};
        #pragma unroll
        for (int k = 0; k < 16; ++k) {
            bf16x8 bb0 = *(const bf16x8*)&s_rm[l15 * RM_STRIDE + k * 32 + q * 8];
            bf16x8 bb1 = *(const bf16x8*)&s_rm[(16 + l15) * RM_STRIDE + k * 32 + q * 8];
            s0 = __builtin_amdgcn_mfma_f32_16x16x32_bf16(afrag[k], bb0, s0, 0, 0, 0);
            s1 = __builtin_amdgcn_mfma_f32_16x16x32_bf16(afrag[k], bb1, s1, 0, 0, 0);
        }

        // ---- P = exp(S); wave-private LDS round-trip; denom via shuffle butterfly
        #pragma unroll
        for (int r = 0; r < 4; ++r) {
            float p0 = __expf(s0[r]);
            float p1 = __expf(s1[r]);
            int xr = q * 4 + r;                  // C-layout row
            prow[xr * P_STRIDE + l15]      = f2bf(p0);
            prow[xr * P_STRIDE + 16 + l15] = f2bf(p1);
            float tsum = p0 + p1;
            tsum += __shfl_xor(tsum, 1, 64);
            tsum += __shfl_xor(tsum, 2, 64);
            tsum += __shfl_xor(tsum, 4, 64);
            tsum += __shfl_xor(tsum, 8, 64);
            dsum[r] += tsum;                     // row sum over this tile's 32 cb
        }

        // ---- O += P @ C : A-frag from wave-private P, B-frags from transposed tile
        bf16x4 pa0 = *(const bf16x4*)&prow[l15 * P_STRIDE + q * 8];
        bf16x4 pa1 = *(const bf16x4*)&prow[l15 * P_STRIDE + q * 8 + 4];
        bf16x8 ap;
        ap[0] = pa0[0]; ap[1] = pa0[1]; ap[2] = pa0[2]; ap[3] = pa0[3];
        ap[4] = pa1[0]; ap[5] = pa1[1]; ap[6] = pa1[2]; ap[7] = pa1[3];
        #pragma unroll
        for (int nt = 0; nt < 32; ++nt) {
            bf16x8 bt = *(const bf16x8*)&s_ct[(nt * 16 + l15) * CT_STRIDE + q * 8];
            acc[nt] = __builtin_amdgcn_mfma_f32_16x16x32_bf16(ap, bt, acc[nt], 0, 0, 0);
        }
    }

    // ---- epilogue: divide by softmax denominator, store
    float inv[4];
    #pragma unroll
    for (int r = 0; r < 4; ++r) inv[r] = 1.0f / dsum[r];
    float* orow = out + (size_t)(wr0 + q * 4) * D_DIM + l15;
    #pragma unroll
    for (int nt = 0; nt < 32; ++nt) {
        #pragma unroll
        for (int r = 0; r < 4; ++r) {
            orow[(size_t)r * D_DIM + nt * 16] = acc[nt][r] * inv[r];
        }
    }
}

extern "C" void kernel_launch(void* const* d_in, const int* in_sizes, int n_in,
                              void* d_out, int out_size, void* d_ws, size_t ws_size,
                              hipStream_t stream) {
    const float* x  = (const float*)d_in[0];
    const float* cb = (const float*)d_in[1];
    unsigned short* cb_rm = (unsigned short*)d_ws;                       // 8 MB
    unsigned short* cb_t  = cb_rm + (size_t)K_CB * D_DIM;                // 8 MB
    float* outp = (float*)d_out;

    prep_codebook<<<NKT, 512, 0, stream>>>(cb, cb_rm, cb_t);
    cbmap_main<<<N_ROWS / BM, 512, 0, stream>>>(x, cb_rm, cb_t, outp);
}

// Round 3
// 800.774 us; speedup vs baseline: 1.2546x; 1.2546x over previous
//
#include <hip/hip_runtime.h>
#include <stdint.h>

#define N_ROWS 32768
#define K_CB   8192
#define D_DIM  512
#define TAU    0.07f
#define BM     128
#define BK     32
#define NKT    256

typedef __attribute__((ext_vector_type(8))) short bf16x8;
typedef __attribute__((ext_vector_type(4))) float f32x4;

__device__ __forceinline__ unsigned short f2bf(float f) {
    unsigned u = __builtin_bit_cast(unsigned, f);
    u += 0x7FFFu + ((u >> 16) & 1u);          // round-to-nearest-even
    return (unsigned short)(u >> 16);
}

__device__ __forceinline__ void glds16(const unsigned short* g, unsigned short* l) {
    __builtin_amdgcn_global_load_lds(
        (const __attribute__((address_space(1))) unsigned int*)g,
        (__attribute__((address_space(3))) unsigned int*)l, 16, 0, 0);
}

__device__ __forceinline__ unsigned comb(unsigned a, unsigned b, bool lo) {
    // word = bf16 for j_even (low16) | bf16 for j_odd (high16)
    return lo ? ((a & 0xffffu) | (b << 16)) : ((a >> 16) | (b & 0xffff0000u));
}

// codebook fp32 [K][512] -> two pre-swizzled bf16 arrays of 16B chunks per 32-row tile:
//  rm_sw: chunk c = cbl*64 + (dc ^ (cbl&7))        holds C[tile cb=cbl][d = dc*8 .. +7]
//  t_sw : chunk c = (d*4 + cbc) ^ ((d>>1)&7)       holds C[tile cb=cbc*8+e][d], e=0..7
__global__ __launch_bounds__(512) void prep_codebook(const float* __restrict__ cb,
                                                     unsigned short* __restrict__ rm_sw,
                                                     unsigned short* __restrict__ t_sw) {
    __shared__ unsigned short tile[32 * 512];     // row-major [cbl][d]
    const int j = blockIdx.x, t = threadIdx.x;
    const float2* src = (const float2*)(cb + (size_t)j * (BK * D_DIM));
    unsigned* t32 = (unsigned*)tile;
    #pragma unroll
    for (int it = 0; it < 16; ++it) {
        int e2 = it * 512 + t;
        float2 v = src[e2];
        t32[e2] = (unsigned)f2bf(v.x) | ((unsigned)f2bf(v.y) << 16);
    }
    __syncthreads();
    uint4* rmd = (uint4*)rm_sw + (size_t)j * 2048;
    uint4* twd = (uint4*)t_sw + (size_t)j * 2048;
    #pragma unroll
    for (int it = 0; it < 4; ++it) {
        int L = it * 512 + t;
        int cbl = L >> 6, dc = L & 63;
        int c = cbl * 64 + (dc ^ (cbl & 7));
        rmd[c] = *(const uint4*)&tile[cbl * 512 + dc * 8];
    }
    #pragma unroll
    for (int it = 0; it < 4; ++it) {
        int M = it * 512 + t;
        int d = M >> 2, cbc = M & 3;
        int c = (d * 4 + cbc) ^ ((d >> 1) & 7);
        unsigned short tmp[8];
        #pragma unroll
        for (int e = 0; e < 8; ++e) tmp[e] = tile[(cbc * 8 + e) * 512 + d];
        twd[c] = *(const uint4*)tmp;
    }
}

__global__ __launch_bounds__(512, 2) void cbmap_main(const float* __restrict__ x,
                                                     const unsigned short* __restrict__ rm_sw,
                                                     const unsigned short* __restrict__ t_sw,
                                                     float* __restrict__ out) {
    __shared__ unsigned short s_rm[2][16384];   // 2 × 32 KB, swizzled cb-major tile
    __shared__ unsigned short s_ct[2][16384];   // 2 × 32 KB, swizzled d-major tile
    __shared__ unsigned short s_px[8][512];     // 8 × 1 KB, P-fragment exchange
    __shared__ float s_ds[128];                 // softmax denominators

    const int tid = threadIdx.x;
    const int w = tid >> 6, lane = tid & 63, l15 = lane & 15, q = lane >> 4;
    const int pairA = w >> 1, dhalf = w & 1;
    const int srow0 = blockIdx.x * BM + w * 16;   // this wave's 16 S-rows

    // ---- prologue: L2-normalize own rows, fold 1/TAU, A-fragments in regs
    const float* xrow = x + (size_t)(srow0 + l15) * D_DIM + q * 8;
    float4 va[16], vb[16];
    float ss = 0.f;
    #pragma unroll
    for (int k = 0; k < 16; ++k) {
        va[k] = *(const float4*)(xrow + k * 32);
        vb[k] = *(const float4*)(xrow + k * 32 + 4);
        ss += va[k].x*va[k].x + va[k].y*va[k].y + va[k].z*va[k].z + va[k].w*va[k].w;
        ss += vb[k].x*vb[k].x + vb[k].y*vb[k].y + vb[k].z*vb[k].z + vb[k].w*vb[k].w;
    }
    ss += __shfl_xor(ss, 16, 64);
    ss += __shfl_xor(ss, 32, 64);
    const float scale = 1.0f / (fmaxf(sqrtf(ss), 1e-12f) * TAU);
    bf16x8 afrag[16];
    #pragma unroll
    for (int k = 0; k < 16; ++k) {
        bf16x8 f;
        f[0] = (short)f2bf(va[k].x * scale); f[1] = (short)f2bf(va[k].y * scale);
        f[2] = (short)f2bf(va[k].z * scale); f[3] = (short)f2bf(va[k].w * scale);
        f[4] = (short)f2bf(vb[k].x * scale); f[5] = (short)f2bf(vb[k].y * scale);
        f[6] = (short)f2bf(vb[k].z * scale); f[7] = (short)f2bf(vb[k].w * scale);
        afrag[k] = f;
    }

    f32x4 acc[2][16];
    #pragma unroll
    for (int mt = 0; mt < 2; ++mt)
        #pragma unroll
        for (int nt = 0; nt < 16; ++nt) acc[mt][nt] = (f32x4){0.f,0.f,0.f,0.f};
    float dsum = 0.f;

    // ---- preload tile 0 -> buffer 0 (async global->LDS, 16B/lane)
    #pragma unroll
    for (int k = 0; k < 4; ++k) {
        glds16(rm_sw + (size_t)(k * 512 + tid) * 8, &s_rm[0][(k * 512 + tid) * 8]);
        glds16(t_sw  + (size_t)(k * 512 + tid) * 8, &s_ct[0][(k * 512 + tid) * 8]);
    }
    __syncthreads();

    const int pxc = (l15 * 4 + (q ^ ((l15 >> 1) & 3))) * 8;  // swizzled px chunk (u16 offset)
    const int sl0 = ((2 * q) & 3) * 16 + l15;
    const int sl1 = ((2 * q + 1) & 3) * 16 + l15;
    const int swz = l15 & 7;

    for (int j = 0; j < NKT; ++j) {
        const int p = j & 1;
        const size_t nb = (size_t)((j + 1) & (NKT - 1)) * 16384;
        // prefetch next tile into the other buffer; drains at end-of-iter barrier
        #pragma unroll
        for (int k = 0; k < 4; ++k) {
            glds16(rm_sw + nb + (size_t)(k * 512 + tid) * 8, &s_rm[p ^ 1][(k * 512 + tid) * 8]);
            glds16(t_sw  + nb + (size_t)(k * 512 + tid) * 8, &s_ct[p ^ 1][(k * 512 + tid) * 8]);
        }

        // ---- S^T = C_tile · x_n^T  (A = cb-frag from LDS, B = x-frag regs)
        f32x4 s0 = (f32x4){0.f,0.f,0.f,0.f};
        f32x4 s1 = (f32x4){0.f,0.f,0.f,0.f};
        const unsigned short* srm = s_rm[p];
        #pragma unroll
        for (int kt = 0; kt < 16; ++kt) {
            int dc = (kt * 4 + q) ^ swz;
            bf16x8 bb0 = *(const bf16x8*)&srm[(l15 * 64 + dc) * 8];
            bf16x8 bb1 = *(const bf16x8*)&srm[((16 + l15) * 64 + dc) * 8];
            s0 = __builtin_amdgcn_mfma_f32_16x16x32_bf16(bb0, afrag[kt], s0, 0, 0, 0);
            s1 = __builtin_amdgcn_mfma_f32_16x16x32_bf16(bb1, afrag[kt], s1, 0, 0, 0);
        }

        // ---- P = exp(S^T): lane(q,l15) holds P[row l15][cb 4q+r] (s0) and [16+4q+r] (s1)
        unsigned pk[4]; float loc = 0.f;
        #pragma unroll
        for (int r = 0; r < 4; ++r) {
            float p0 = __expf(s0[r]), p1 = __expf(s1[r]);
            loc += p0 + p1;
            pk[r] = (unsigned)f2bf(p0) | ((unsigned)f2bf(p1) << 16);
        }
        loc += __shfl_xor(loc, 16, 64);
        loc += __shfl_xor(loc, 32, 64);
        dsum += loc;          // full row-l15 sum for this tile (replicated over quads)

        // ---- in-register transpose to PV A-layout: lane(q,l15) <- P[l15][8q+j], j=0..7
        unsigned sh0[4], sh1[4];
        #pragma unroll
        for (int r = 0; r < 4; ++r) {
            sh0[r] = (unsigned)__shfl((int)pk[r], sl0, 64);
            sh1[r] = (unsigned)__shfl((int)pk[r], sl1, 64);
        }
        const bool lo = (q < 2);
        uint4 apv;
        apv.x = comb(sh0[0], sh0[1], lo);
        apv.y = comb(sh0[2], sh0[3], lo);
        apv.z = comb(sh1[0], sh1[1], lo);
        apv.w = comb(sh1[2], sh1[3], lo);
        *(uint4*)&s_px[w][pxc] = apv;
        __syncthreads();                         // B1: px visible

        bf16x8 ap0 = *(const bf16x8*)&s_px[pairA * 2][pxc];      // rows 0..15 of pair
        bf16x8 ap1 = *(const bf16x8*)&s_px[pairA * 2 + 1][pxc];  // rows 16..31 of pair

        // ---- O += P · C_tile over this wave's d-half (f=2 pairing)
        const unsigned short* sct = s_ct[p];
        #pragma unroll
        for (int nt = 0; nt < 16; ++nt) {
            int dd = dhalf * 256 + nt * 16 + l15;
            int c = (dd * 4 + q) ^ ((dd >> 1) & 7);
            bf16x8 bt = *(const bf16x8*)&sct[c * 8];
            acc[0][nt] = __builtin_amdgcn_mfma_f32_16x16x32_bf16(ap0, bt, acc[0][nt], 0, 0, 0);
            acc[1][nt] = __builtin_amdgcn_mfma_f32_16x16x32_bf16(ap1, bt, acc[1][nt], 0, 0, 0);
        }
        __syncthreads();                         // B2: buf reads done + prefetch drained
    }

    // ---- epilogue: exchange denominators, divide, store
    if (lane < 16) s_ds[w * 16 + lane] = dsum;
    __syncthreads();
    const int prow0 = pairA * 32;
    float* ob = out + ((size_t)blockIdx.x * BM + prow0) * D_DIM + dhalf * 256 + l15;
    #pragma unroll
    for (int mt = 0; mt < 2; ++mt) {
        #pragma unroll
        for (int r = 0; r < 4; ++r) {
            float inv = 1.0f / s_ds[prow0 + mt * 16 + q * 4 + r];
            #pragma unroll
            for (int nt = 0; nt < 16; ++nt) {
                ob[(size_t)(mt * 16 + q * 4 + r) * D_DIM + nt * 16] = acc[mt][nt][r] * inv;
            }
        }
    }
}

extern "C" void kernel_launch(void* const* d_in, const int* in_sizes, int n_in,
                              void* d_out, int out_size, void* d_ws, size_t ws_size,
                              hipStream_t stream) {
    const float* x  = (const float*)d_in[0];
    const float* cb = (const float*)d_in[1];
    unsigned short* rm_sw = (unsigned short*)d_ws;                       // 8 MB
    unsigned short* t_sw  = rm_sw + (size_t)K_CB * D_DIM;                // 8 MB
    float* outp = (float*)d_out;

    prep_codebook<<<NKT, 512, 0, stream>>>(cb, rm_sw, t_sw);
    cbmap_main<<<N_ROWS / BM, 512, 0, stream>>>(x, rm_sw, t_sw, outp);
}